// Round 4
// baseline (2193.423 us; speedup 1.0000x reference)
//
#include <hip/hip_runtime.h>

typedef unsigned short u16;
typedef unsigned int   u32;

#define D_MODEL 1024
#define D_INNER 2048
#define D_STATE 16
#define SEQLEN  2048
#define BATCH   4
#define NROWS   (BATCH*SEQLEN)   // 8192

__device__ __forceinline__ float b2f(u16 v){
  union { u32 i; float f; } u; u.i = ((u32)v) << 16; return u.f;
}
__device__ __forceinline__ u16 f2b(float f){
  union { float f; u32 i; } u; u.f = f;
  u32 x = u.i;
  return (u16)((x + 0x7fffu + ((x >> 16) & 1u)) >> 16);  // RNE
}
__device__ __forceinline__ float h2f(u16 v){
  _Float16 h; __builtin_memcpy(&h, &v, 2); return (float)h;
}
__device__ __forceinline__ u16 f2h(float f){
  _Float16 h = (_Float16)f; u16 v; __builtin_memcpy(&v, &h, 2); return v;
}

typedef __bf16 bf16x8 __attribute__((ext_vector_type(8)));
typedef float  f32x4  __attribute__((ext_vector_type(4)));

// ---------------------------------------------------------------------------
// fp32 -> bf16 weight conversion (n % 1024 == 0)
// ---------------------------------------------------------------------------
__global__ __launch_bounds__(256) void wcvt_kernel(
    const float* __restrict__ w, u16* __restrict__ wb, int n)
{
  const int i = (blockIdx.x*256 + threadIdx.x) * 4;
  if (i >= n) return;
  float4 v = *reinterpret_cast<const float4*>(w + i);
  ushort4 o;
  o.x = f2b(v.x); o.y = f2b(v.y); o.z = f2b(v.z); o.w = f2b(v.w);
  *reinterpret_cast<ushort4*>(wb + i) = o;
}

// ---------------------------------------------------------------------------
// Fused LayerNorm: x[row][1024] fp32 -> xn bf16
// ---------------------------------------------------------------------------
__global__ __launch_bounds__(256) void ln_kernel(
    const float* __restrict__ x, const float* __restrict__ g,
    const float* __restrict__ be, u16* __restrict__ xn)
{
  const int row = blockIdx.x;
  const float* xr = x + (size_t)row * D_MODEL;
  const int tid = threadIdx.x;
  float v[4]; float s = 0.f, s2 = 0.f;
  #pragma unroll
  for (int j=0;j<4;j++){
    float f = xr[tid + 256*j];
    v[j] = f; s += f; s2 += f*f;
  }
  #pragma unroll
  for (int o=32;o>0;o>>=1){ s += __shfl_down(s,o); s2 += __shfl_down(s2,o); }
  __shared__ float sh[8];
  const int wave = tid>>6, lane = tid&63;
  if (lane==0){ sh[wave]=s; sh[4+wave]=s2; }
  __syncthreads();
  const float ts  = sh[0]+sh[1]+sh[2]+sh[3];
  const float ts2 = sh[4]+sh[5]+sh[6]+sh[7];
  const float mu  = ts * (1.f/D_MODEL);
  const float var = ts2 * (1.f/D_MODEL) - mu*mu;
  const float rstd = rsqrtf(var + 1e-5f);
  u16* xo = xn + (size_t)row * D_MODEL;
  #pragma unroll
  for (int j=0;j<4;j++){
    int i = tid + 256*j;
    xo[i] = f2b((v[j]-mu)*rstd * g[i] + be[i]);
  }
}

// ---------------------------------------------------------------------------
// bf16 MFMA GEMM: C[M,N] = A[M,K] @ Bw[K,N]  (row-major; A,Bw bf16)
// EPI 0: bf16 out ; EPI 1: softplus(v + bias_f32) -> fp16 ; EPI 2: v + resid_f32 -> FP32
// Tile 64x64x32, block=256 (4 waves), wave w does rows w*16..w*16+15, 4 n-tiles.
// Bs stored transposed so both fragments are contiguous 16B LDS reads.
// STR=40 elems (80B rows): 16B-aligned, only 2-way bank aliasing (free, m136).
// ---------------------------------------------------------------------------
template<int EPI>
__global__ __launch_bounds__(256) void gemm_mfma(
    const u16* __restrict__ A, const u16* __restrict__ Bw,
    const float* __restrict__ bias, const float* __restrict__ resid,
    void* __restrict__ outv, int M, int N, int K)
{
  constexpr int STR = 40;
  __shared__ __align__(16) u16 As[64*STR];
  __shared__ __align__(16) u16 Bs[64*STR];
  const int tid  = threadIdx.x;
  const int m0   = blockIdx.y * 64;
  const int n0   = blockIdx.x * 64;
  const int wave = tid >> 6, lane = tid & 63;
  const int quad = lane >> 4, l16 = lane & 15;
  const int a_row = tid >> 2, a_col = (tid & 3) * 8;   // A: 64 rows x 32 k
  const int b_k   = tid >> 3, b_n   = (tid & 7) * 8;   // B: 32 k x 64 n

  f32x4 acc[4];
  #pragma unroll
  for (int i=0;i<4;i++) acc[i] = (f32x4){0.f,0.f,0.f,0.f};

  for (int k0 = 0; k0 < K; k0 += 32) {
    uint4 av = *reinterpret_cast<const uint4*>(A  + (size_t)(m0 + a_row)*K + k0 + a_col);
    uint4 bv = *reinterpret_cast<const uint4*>(Bw + (size_t)(k0 + b_k)*N  + n0 + b_n);
    __syncthreads();
    *reinterpret_cast<uint4*>(&As[a_row*STR + a_col]) = av;
    const u16* bs = reinterpret_cast<const u16*>(&bv);
    #pragma unroll
    for (int j=0;j<8;j++) Bs[(b_n + j)*STR + b_k] = bs[j];  // transpose store
    __syncthreads();
    bf16x8 af = *reinterpret_cast<const bf16x8*>(&As[(wave*16 + l16)*STR + quad*8]);
    #pragma unroll
    for (int nt=0; nt<4; nt++) {
      bf16x8 bfr = *reinterpret_cast<const bf16x8*>(&Bs[(nt*16 + l16)*STR + quad*8]);
      acc[nt] = __builtin_amdgcn_mfma_f32_16x16x32_bf16(af, bfr, acc[nt], 0, 0, 0);
    }
  }

  #pragma unroll
  for (int nt=0; nt<4; nt++) {
    const int col = n0 + nt*16 + l16;
    #pragma unroll
    for (int j=0;j<4;j++) {
      const int row = m0 + wave*16 + quad*4 + j;
      float v = acc[nt][j];
      if (EPI == 1) {
        v += bias[col];
        v = (v > 20.f) ? v : log1pf(__expf(v));
        ((u16*)outv)[(size_t)row*N + col] = f2h(v);       // delta fp16
      } else if (EPI == 2) {
        v += resid[(size_t)row*N + col];
        ((float*)outv)[(size_t)row*N + col] = v;          // final out FP32
      } else {
        ((u16*)outv)[(size_t)row*N + col] = f2b(v);       // bf16 activation
      }
    }
  }
}

// ---------------------------------------------------------------------------
// Causal depthwise conv(width 4) + bias + SiLU.  u_pre = xz[:, 0:2048] (bf16).
// ---------------------------------------------------------------------------
__global__ __launch_bounds__(256) void conv_silu_kernel(
    const u16* __restrict__ xz, const float* __restrict__ cw,
    const float* __restrict__ cb, u16* __restrict__ u)
{
  const int idx = blockIdx.x*256 + threadIdx.x;  // = bt*2048 + c
  const int c  = idx & (D_INNER-1);
  const int t  = (idx >> 11) & (SEQLEN-1);
  const int bt = idx >> 11;
  float acc = cb[c];
  #pragma unroll
  for (int k=0;k<4;k++){
    int tt = t - 3 + k;
    if (tt >= 0)
      acc += cw[c*4 + k] * b2f(xz[(size_t)(bt - 3 + k)*4096 + c]);
  }
  float sv = acc / (1.f + __expf(-acc));
  u[(size_t)bt*D_INNER + c] = f2b(sv);
}

// ---------------------------------------------------------------------------
// x_proj: only cols 16..31 (the B matrix) are consumed downstream.
// One wave per row; lane = kq*16 + n; 4-way K-split then butterfly combine.
// ---------------------------------------------------------------------------
__global__ __launch_bounds__(256) void xproj_kernel(
    const u16* __restrict__ u, const float* __restrict__ W, float* __restrict__ Bm)
{
  const int wave = threadIdx.x >> 6, lane = threadIdx.x & 63;
  const int m = blockIdx.x*4 + wave;
  const int n = lane & 15, kq = lane >> 4;
  const u16* ur = u + (size_t)m*D_INNER + (size_t)kq*512;
  float acc = 0.f;
  for (int i=0;i<512;i++)
    acc += b2f(ur[i]) * W[(size_t)(kq*512 + i)*32 + 16 + n];
  acc += __shfl_xor(acc, 16);
  acc += __shfl_xor(acc, 32);
  if (lane < 16) Bm[(size_t)m*16 + n] = acc;
}

// ---------------------------------------------------------------------------
// Selective scan: thread = (b,c); h[16],A[16] in regs; B chunk (128 t) in LDS.
// Reads u (bf16), delta (fp16), z (bf16 from xz); writes y*silu(z) IN-PLACE
// over u (each (b,c) column owned by one thread; element read precedes write).
// ---------------------------------------------------------------------------
__global__ __launch_bounds__(256) void scan_kernel(
    u16* __restrict__ uu,              // in: u ; out: yg (in-place)
    const u16* __restrict__ delta16,
    const float* __restrict__ Bm,
    const u16* __restrict__ xz,
    const float* __restrict__ Alog, const float* __restrict__ Dpar)
{
  const int b = blockIdx.y;
  const int c = blockIdx.x*256 + threadIdx.x;
  const int row0 = b * SEQLEN;
  float A[16], h[16];
  #pragma unroll
  for (int s=0;s<16;s++){
    A[s] = -__expf(Alog[c*16 + s]);
    h[s] = 0.f;
  }
  const float Dc = Dpar[c];
  __shared__ float Bsh[128*16];

  for (int t0=0; t0<SEQLEN; t0+=128){
    __syncthreads();
    const float* src = Bm + (size_t)(row0 + t0)*16;
    #pragma unroll
    for (int j=0;j<8;j++) Bsh[threadIdx.x + 256*j] = src[threadIdx.x + 256*j];
    __syncthreads();
    for (int tl=0; tl<128; tl++){
      const size_t r = (size_t)(row0 + t0 + tl);
      float dt = h2f(delta16[r*D_INNER + c]);
      float uv = b2f(uu[r*D_INNER + c]);
      float zv = b2f(xz[r*4096 + D_INNER + c]);
      float xv = dt*uv, y = 0.f;
      const float* Bt = &Bsh[tl*16];
      #pragma unroll
      for (int s=0;s<16;s++){
        float dA = __expf(dt*A[s]);
        h[s] = fmaf(h[s], dA, xv*Bt[s]);
        y += h[s];
      }
      y = fmaf(uv, Dc, y);
      float gz = zv/(1.f+__expf(-zv));
      uu[r*D_INNER + c] = f2b(y*gz);
    }
  }
}

// ---------------------------------------------------------------------------
extern "C" void kernel_launch(void* const* d_in, const int* in_sizes, int n_in,
                              void* d_out, int out_size, void* d_ws, size_t ws_size,
                              hipStream_t stream)
{
  const float* x    = (const float*)d_in[0];
  const float* lng  = (const float*)d_in[1];
  const float* lnb  = (const float*)d_in[2];
  const float* W1   = (const float*)d_in[3];
  const float* cw   = (const float*)d_in[4];
  const float* cb   = (const float*)d_in[5];
  const float* Wx   = (const float*)d_in[6];
  const float* Wdt  = (const float*)d_in[7];
  const float* dtb  = (const float*)d_in[8];
  const float* Alog = (const float*)d_in[9];
  const float* Dpar = (const float*)d_in[10];
  const float* Wout = (const float*)d_in[11];

  // workspace layout (MiB offsets), total 149 MiB:
  //  [0,32)      delta fp16 8192x2048   (first 16 MiB doubles as xn bf16: dead
  //  [0,16)      xn bf16 8192x1024       before gemm1 writes delta)
  //  [32,96)     xz bf16 8192x4096
  //  [96,128)    uu bf16 8192x2048      (conv out; scan overwrites in-place)
  //  [128,128.5) Bm fp32 8192x16
  //  [129,137)   W1b   bf16 1024x4096
  //  [137,145)   Wdtb  bf16 2048x2048
  //  [145,149)   Woutb bf16 2048x1024
  char* ws = (char*)d_ws;
  u16*   dlt   = (u16*)(ws);
  u16*   xn    = (u16*)(ws);                 // alias (sequenced: dead pre-gemm1)
  u16*   xz    = (u16*)(ws + (32llu<<20));
  u16*   uu    = (u16*)(ws + (96llu<<20));
  float* Bm    = (float*)(ws + (128llu<<20));
  u16*   W1b   = (u16*)(ws + (129llu<<20));
  u16*   Wdtb  = (u16*)(ws + (137llu<<20));
  u16*   Woutb = (u16*)(ws + (145llu<<20));

  wcvt_kernel<<<(D_MODEL*2*D_INNER)/1024, 256, 0, stream>>>(W1,  W1b,  D_MODEL*2*D_INNER);
  wcvt_kernel<<<(D_INNER*D_INNER)/1024,  256, 0, stream>>>(Wdt, Wdtb, D_INNER*D_INNER);
  wcvt_kernel<<<(D_INNER*D_MODEL)/1024,  256, 0, stream>>>(Wout,Woutb,D_INNER*D_MODEL);

  ln_kernel<<<NROWS, 256, 0, stream>>>(x, lng, lnb, xn);

  gemm_mfma<0><<<dim3(2*D_INNER/64, NROWS/64), 256, 0, stream>>>(
      xn, W1b, nullptr, nullptr, (void*)xz, NROWS, 2*D_INNER, D_MODEL);

  conv_silu_kernel<<<(NROWS*D_INNER)/256, 256, 0, stream>>>(xz, cw, cb, uu);

  xproj_kernel<<<NROWS/4, 256, 0, stream>>>(uu, Wx, Bm);

  gemm_mfma<1><<<dim3(D_INNER/64, NROWS/64), 256, 0, stream>>>(
      uu, Wdtb, dtb, nullptr, (void*)dlt, NROWS, D_INNER, D_INNER);

  scan_kernel<<<dim3(D_INNER/256, BATCH), 256, 0, stream>>>(
      uu, dlt, Bm, xz, Alog, Dpar);

  gemm_mfma<2><<<dim3(D_MODEL/64, NROWS/64), 256, 0, stream>>>(
      uu, Woutb, nullptr, x, d_out, NROWS, D_MODEL, D_INNER);

  (void)in_sizes; (void)n_in; (void)out_size; (void)ws_size;
}

// Round 5
// 1262.860 us; speedup vs baseline: 1.7369x; 1.7369x over previous
//
#include <hip/hip_runtime.h>

typedef unsigned short u16;
typedef unsigned int   u32;

#define D_MODEL 1024
#define D_INNER 2048
#define D_STATE 16
#define SEQLEN  2048
#define BATCH   4
#define NROWS   (BATCH*SEQLEN)   // 8192
#define CHUNK   128
#define NCHUNK  (SEQLEN/CHUNK)   // 16

__device__ __forceinline__ float b2f(u16 v){
  union { u32 i; float f; } u; u.i = ((u32)v) << 16; return u.f;
}
__device__ __forceinline__ u16 f2b(float f){
  union { float f; u32 i; } u; u.f = f;
  u32 x = u.i;
  return (u16)((x + 0x7fffu + ((x >> 16) & 1u)) >> 16);  // RNE
}
__device__ __forceinline__ float h2f(u16 v){
  _Float16 h; __builtin_memcpy(&h, &v, 2); return (float)h;
}
__device__ __forceinline__ u16 f2h(float f){
  _Float16 h = (_Float16)f; u16 v; __builtin_memcpy(&v, &h, 2); return v;
}

typedef __bf16 bf16x8 __attribute__((ext_vector_type(8)));
typedef float  f32x4  __attribute__((ext_vector_type(4)));

// ---------------------------------------------------------------------------
// fp32 -> bf16 weight conversion (n % 1024 == 0)
// ---------------------------------------------------------------------------
__global__ __launch_bounds__(256) void wcvt_kernel(
    const float* __restrict__ w, u16* __restrict__ wb, int n)
{
  const int i = (blockIdx.x*256 + threadIdx.x) * 4;
  if (i >= n) return;
  float4 v = *reinterpret_cast<const float4*>(w + i);
  ushort4 o;
  o.x = f2b(v.x); o.y = f2b(v.y); o.z = f2b(v.z); o.w = f2b(v.w);
  *reinterpret_cast<ushort4*>(wb + i) = o;
}

// ---------------------------------------------------------------------------
// Fused LayerNorm: x[row][1024] fp32 -> xn bf16
// ---------------------------------------------------------------------------
__global__ __launch_bounds__(256) void ln_kernel(
    const float* __restrict__ x, const float* __restrict__ g,
    const float* __restrict__ be, u16* __restrict__ xn)
{
  const int row = blockIdx.x;
  const float* xr = x + (size_t)row * D_MODEL;
  const int tid = threadIdx.x;
  float v[4]; float s = 0.f, s2 = 0.f;
  #pragma unroll
  for (int j=0;j<4;j++){
    float f = xr[tid + 256*j];
    v[j] = f; s += f; s2 += f*f;
  }
  #pragma unroll
  for (int o=32;o>0;o>>=1){ s += __shfl_down(s,o); s2 += __shfl_down(s2,o); }
  __shared__ float sh[8];
  const int wave = tid>>6, lane = tid&63;
  if (lane==0){ sh[wave]=s; sh[4+wave]=s2; }
  __syncthreads();
  const float ts  = sh[0]+sh[1]+sh[2]+sh[3];
  const float ts2 = sh[4]+sh[5]+sh[6]+sh[7];
  const float mu  = ts * (1.f/D_MODEL);
  const float var = ts2 * (1.f/D_MODEL) - mu*mu;
  const float rstd = rsqrtf(var + 1e-5f);
  u16* xo = xn + (size_t)row * D_MODEL;
  #pragma unroll
  for (int j=0;j<4;j++){
    int i = tid + 256*j;
    xo[i] = f2b((v[j]-mu)*rstd * g[i] + be[i]);
  }
}

// ---------------------------------------------------------------------------
// bf16 MFMA GEMM: C[M,N] = A[M,K] @ Bw[K,N]  (row-major; A,Bw bf16)
// EPI 0: bf16 out ; EPI 1: softplus(v + bias_f32) -> fp16 ; EPI 2: v + resid_f32 -> FP32
// Tile 64x64x32, block=256 (4 waves).
// ---------------------------------------------------------------------------
template<int EPI>
__global__ __launch_bounds__(256) void gemm_mfma(
    const u16* __restrict__ A, const u16* __restrict__ Bw,
    const float* __restrict__ bias, const float* __restrict__ resid,
    void* __restrict__ outv, int M, int N, int K)
{
  constexpr int STR = 40;
  __shared__ __align__(16) u16 As[64*STR];
  __shared__ __align__(16) u16 Bs[64*STR];
  const int tid  = threadIdx.x;
  const int m0   = blockIdx.y * 64;
  const int n0   = blockIdx.x * 64;
  const int wave = tid >> 6, lane = tid & 63;
  const int quad = lane >> 4, l16 = lane & 15;
  const int a_row = tid >> 2, a_col = (tid & 3) * 8;   // A: 64 rows x 32 k
  const int b_k   = tid >> 3, b_n   = (tid & 7) * 8;   // B: 32 k x 64 n

  f32x4 acc[4];
  #pragma unroll
  for (int i=0;i<4;i++) acc[i] = (f32x4){0.f,0.f,0.f,0.f};

  for (int k0 = 0; k0 < K; k0 += 32) {
    uint4 av = *reinterpret_cast<const uint4*>(A  + (size_t)(m0 + a_row)*K + k0 + a_col);
    uint4 bv = *reinterpret_cast<const uint4*>(Bw + (size_t)(k0 + b_k)*N  + n0 + b_n);
    __syncthreads();
    *reinterpret_cast<uint4*>(&As[a_row*STR + a_col]) = av;
    const u16* bs = reinterpret_cast<const u16*>(&bv);
    #pragma unroll
    for (int j=0;j<8;j++) Bs[(b_n + j)*STR + b_k] = bs[j];  // transpose store
    __syncthreads();
    bf16x8 af = *reinterpret_cast<const bf16x8*>(&As[(wave*16 + l16)*STR + quad*8]);
    #pragma unroll
    for (int nt=0; nt<4; nt++) {
      bf16x8 bfr = *reinterpret_cast<const bf16x8*>(&Bs[(nt*16 + l16)*STR + quad*8]);
      acc[nt] = __builtin_amdgcn_mfma_f32_16x16x32_bf16(af, bfr, acc[nt], 0, 0, 0);
    }
  }

  #pragma unroll
  for (int nt=0; nt<4; nt++) {
    const int col = n0 + nt*16 + l16;
    #pragma unroll
    for (int j=0;j<4;j++) {
      const int row = m0 + wave*16 + quad*4 + j;
      float v = acc[nt][j];
      if (EPI == 1) {
        v += bias[col];
        v = (v > 20.f) ? v : log1pf(__expf(v));
        ((u16*)outv)[(size_t)row*N + col] = f2h(v);       // delta fp16
      } else if (EPI == 2) {
        v += resid[(size_t)row*N + col];
        ((float*)outv)[(size_t)row*N + col] = v;          // final out FP32
      } else {
        ((u16*)outv)[(size_t)row*N + col] = f2b(v);       // bf16 activation
      }
    }
  }
}

// ---------------------------------------------------------------------------
// Causal depthwise conv(width 4) + bias + SiLU.  u_pre = xz[:, 0:2048] (bf16).
// ---------------------------------------------------------------------------
__global__ __launch_bounds__(256) void conv_silu_kernel(
    const u16* __restrict__ xz, const float* __restrict__ cw,
    const float* __restrict__ cb, u16* __restrict__ u)
{
  const int idx = blockIdx.x*256 + threadIdx.x;  // = bt*2048 + c
  const int c  = idx & (D_INNER-1);
  const int t  = (idx >> 11) & (SEQLEN-1);
  const int bt = idx >> 11;
  float acc = cb[c];
  #pragma unroll
  for (int k=0;k<4;k++){
    int tt = t - 3 + k;
    if (tt >= 0)
      acc += cw[c*4 + k] * b2f(xz[(size_t)(bt - 3 + k)*4096 + c]);
  }
  float sv = acc / (1.f + __expf(-acc));
  u[(size_t)bt*D_INNER + c] = f2b(sv);
}

// ---------------------------------------------------------------------------
// x_proj: only cols 16..31 (the B matrix) are consumed downstream.
// ---------------------------------------------------------------------------
__global__ __launch_bounds__(256) void xproj_kernel(
    const u16* __restrict__ u, const float* __restrict__ W, float* __restrict__ Bm)
{
  const int wave = threadIdx.x >> 6, lane = threadIdx.x & 63;
  const int m = blockIdx.x*4 + wave;
  const int n = lane & 15, kq = lane >> 4;
  const u16* ur = u + (size_t)m*D_INNER + (size_t)kq*512;
  float acc = 0.f;
  for (int i=0;i<512;i++)
    acc += b2f(ur[i]) * W[(size_t)(kq*512 + i)*32 + 16 + n];
  acc += __shfl_xor(acc, 16);
  acc += __shfl_xor(acc, 32);
  if (lane < 16) Bm[(size_t)m*16 + n] = acc;
}

// ---------------------------------------------------------------------------
// Chunked selective scan, 3 passes (exact linear-recurrence decomposition):
//   h_t = h_{t-1}*exp(dt_t*A) + (dt_t*u_t)*B_t
//   prod over chunk of exp(dt*A) = exp(A * sum(dt))  -> 1 exp per chunk/state
// Pass A: per (b,c,chunk) local scan from 0 -> h_end[16], sum(dt)
// Pass B: per (b,c) sequential combine over 16 chunks -> h_in per chunk
// Pass C: per (b,c,chunk) rerun recurrence from h_in, gate, write yg
// ---------------------------------------------------------------------------
__global__ __launch_bounds__(256) void scan_partial(
    const u16* __restrict__ uu, const u16* __restrict__ delta16,
    const float* __restrict__ Bm, const float* __restrict__ Alog,
    float* __restrict__ hend, float* __restrict__ sumdt)
{
  const int b = blockIdx.y, ch = blockIdx.z;
  const int c = blockIdx.x*256 + threadIdx.x;
  const int row0 = b*SEQLEN + ch*CHUNK;
  float A[16], h[16];
  #pragma unroll
  for (int s=0;s<16;s++){ A[s] = -__expf(Alog[c*16+s]); h[s]=0.f; }
  __shared__ float Bsh[CHUNK*16];
  const float* src = Bm + (size_t)row0*16;
  #pragma unroll
  for (int j=0;j<8;j++) Bsh[threadIdx.x + 256*j] = src[threadIdx.x + 256*j];
  __syncthreads();

  float S = 0.f;
  float dta[8], uva[8], dtb[8], uvb[8];
  #pragma unroll
  for (int j=0;j<8;j++){
    size_t r = (size_t)(row0+j);
    dta[j] = h2f(delta16[r*D_INNER+c]);
    uva[j] = b2f(uu[r*D_INNER+c]);
  }
  #pragma unroll 1
  for (int g=0; g<CHUNK; g+=16){
    #pragma unroll
    for (int j=0;j<8;j++){
      int tl = g+8+j; tl = tl < CHUNK ? tl : CHUNK-1;
      size_t r = (size_t)(row0+tl);
      dtb[j] = h2f(delta16[r*D_INNER+c]);
      uvb[j] = b2f(uu[r*D_INNER+c]);
    }
    #pragma unroll
    for (int j=0;j<8;j++){
      float dt=dta[j], uv=uva[j]; S += dt; float xv=dt*uv;
      const float* Bt = &Bsh[(g+j)*16];
      #pragma unroll
      for (int s=0;s<16;s++) h[s] = fmaf(h[s], __expf(dt*A[s]), xv*Bt[s]);
    }
    #pragma unroll
    for (int j=0;j<8;j++){
      int tl = g+16+j; tl = tl < CHUNK ? tl : CHUNK-1;
      size_t r = (size_t)(row0+tl);
      dta[j] = h2f(delta16[r*D_INNER+c]);
      uva[j] = b2f(uu[r*D_INNER+c]);
    }
    #pragma unroll
    for (int j=0;j<8;j++){
      float dt=dtb[j], uv=uvb[j]; S += dt; float xv=dt*uv;
      const float* Bt = &Bsh[(g+8+j)*16];
      #pragma unroll
      for (int s=0;s<16;s++) h[s] = fmaf(h[s], __expf(dt*A[s]), xv*Bt[s]);
    }
  }
  const size_t base = ((size_t)(b*NCHUNK+ch)*16)*D_INNER + c;
  #pragma unroll
  for (int s=0;s<16;s++) hend[base + (size_t)s*D_INNER] = h[s];
  sumdt[(size_t)(b*NCHUNK+ch)*D_INNER + c] = S;
}

__global__ __launch_bounds__(256) void scan_combine(
    const float* __restrict__ hend, const float* __restrict__ sumdt,
    const float* __restrict__ Alog, float* __restrict__ hin)
{
  const int b = blockIdx.y;
  const int c = blockIdx.x*256 + threadIdx.x;
  float A[16], h[16];
  #pragma unroll
  for (int s=0;s<16;s++){ A[s] = -__expf(Alog[c*16+s]); h[s]=0.f; }
  #pragma unroll 1
  for (int k=0;k<NCHUNK;k++){
    const size_t base = ((size_t)(b*NCHUNK+k)*16)*D_INNER + c;
    #pragma unroll
    for (int s=0;s<16;s++) hin[base + (size_t)s*D_INNER] = h[s];
    const float S = sumdt[(size_t)(b*NCHUNK+k)*D_INNER + c];
    #pragma unroll
    for (int s=0;s<16;s++)
      h[s] = fmaf(h[s], __expf(S*A[s]), hend[base + (size_t)s*D_INNER]);
  }
}

__global__ __launch_bounds__(256) void scan_final(
    const u16* __restrict__ uu, const u16* __restrict__ delta16,
    const float* __restrict__ Bm, const u16* __restrict__ xz,
    const float* __restrict__ Alog, const float* __restrict__ Dpar,
    const float* __restrict__ hin, u16* __restrict__ yg)
{
  const int b = blockIdx.y, ch = blockIdx.z;
  const int c = blockIdx.x*256 + threadIdx.x;
  const int row0 = b*SEQLEN + ch*CHUNK;
  float A[16], h[16];
  const size_t base = ((size_t)(b*NCHUNK+ch)*16)*D_INNER + c;
  #pragma unroll
  for (int s=0;s<16;s++){
    A[s] = -__expf(Alog[c*16+s]);
    h[s] = hin[base + (size_t)s*D_INNER];
  }
  const float Dc = Dpar[c];
  __shared__ float Bsh[CHUNK*16];
  const float* src = Bm + (size_t)row0*16;
  #pragma unroll
  for (int j=0;j<8;j++) Bsh[threadIdx.x + 256*j] = src[threadIdx.x + 256*j];
  __syncthreads();

  float dta[8], uva[8], zva[8], dtb[8], uvb[8], zvb[8];
  #pragma unroll
  for (int j=0;j<8;j++){
    size_t r = (size_t)(row0+j);
    dta[j] = h2f(delta16[r*D_INNER+c]);
    uva[j] = b2f(uu[r*D_INNER+c]);
    zva[j] = b2f(xz[r*4096 + D_INNER + c]);
  }
  #pragma unroll 1
  for (int g=0; g<CHUNK; g+=16){
    #pragma unroll
    for (int j=0;j<8;j++){
      int tl = g+8+j; tl = tl < CHUNK ? tl : CHUNK-1;
      size_t r = (size_t)(row0+tl);
      dtb[j] = h2f(delta16[r*D_INNER+c]);
      uvb[j] = b2f(uu[r*D_INNER+c]);
      zvb[j] = b2f(xz[r*4096 + D_INNER + c]);
    }
    #pragma unroll
    for (int j=0;j<8;j++){
      float dt=dta[j], uv=uva[j], zv=zva[j];
      float xv=dt*uv, y=0.f;
      const float* Bt = &Bsh[(g+j)*16];
      #pragma unroll
      for (int s=0;s<16;s++){
        h[s] = fmaf(h[s], __expf(dt*A[s]), xv*Bt[s]);
        y += h[s];
      }
      y = fmaf(uv, Dc, y);
      float gz = zv/(1.f+__expf(-zv));
      yg[(size_t)(row0+g+j)*D_INNER + c] = f2b(y*gz);
    }
    #pragma unroll
    for (int j=0;j<8;j++){
      int tl = g+16+j; tl = tl < CHUNK ? tl : CHUNK-1;
      size_t r = (size_t)(row0+tl);
      dta[j] = h2f(delta16[r*D_INNER+c]);
      uva[j] = b2f(uu[r*D_INNER+c]);
      zva[j] = b2f(xz[r*4096 + D_INNER + c]);
    }
    #pragma unroll
    for (int j=0;j<8;j++){
      float dt=dtb[j], uv=uvb[j], zv=zvb[j];
      float xv=dt*uv, y=0.f;
      const float* Bt = &Bsh[(g+8+j)*16];
      #pragma unroll
      for (int s=0;s<16;s++){
        h[s] = fmaf(h[s], __expf(dt*A[s]), xv*Bt[s]);
        y += h[s];
      }
      y = fmaf(uv, Dc, y);
      float gz = zv/(1.f+__expf(-zv));
      yg[(size_t)(row0+g+8+j)*D_INNER + c] = f2b(y*gz);
    }
  }
}

// ---------------------------------------------------------------------------
extern "C" void kernel_launch(void* const* d_in, const int* in_sizes, int n_in,
                              void* d_out, int out_size, void* d_ws, size_t ws_size,
                              hipStream_t stream)
{
  const float* x    = (const float*)d_in[0];
  const float* lng  = (const float*)d_in[1];
  const float* lnb  = (const float*)d_in[2];
  const float* W1   = (const float*)d_in[3];
  const float* cw   = (const float*)d_in[4];
  const float* cb   = (const float*)d_in[5];
  const float* Wx   = (const float*)d_in[6];
  const float* Wdt  = (const float*)d_in[7];
  const float* dtb  = (const float*)d_in[8];
  const float* Alog = (const float*)d_in[9];
  const float* Dpar = (const float*)d_in[10];
  const float* Wout = (const float*)d_in[11];

  // workspace layout (MiB offsets), total 198 MiB:
  //  [0,32)      delta fp16 8192x2048   ([0,16) doubles as xn bf16, dead pre-gemm1)
  //  [32,96)     xz bf16 8192x4096
  //  [96,128)    uu bf16 8192x2048
  //  [128,128.5) Bm fp32 8192x16
  //  [129,137)   W1b bf16 ; [137,145) Wdtb bf16 ; [145,149) Woutb bf16
  //  [149,181)   yg bf16 8192x2048
  //  [181,189)   hend fp32 4*16*16*2048
  //  [189,189.5) sumdt fp32 4*16*2048
  //  [190,198)   hin fp32 4*16*16*2048
  char* ws = (char*)d_ws;
  u16*   dlt   = (u16*)(ws);
  u16*   xn    = (u16*)(ws);                 // alias (sequenced)
  u16*   xz    = (u16*)(ws + (32llu<<20));
  u16*   uu    = (u16*)(ws + (96llu<<20));
  float* Bm    = (float*)(ws + (128llu<<20));
  u16*   W1b   = (u16*)(ws + (129llu<<20));
  u16*   Wdtb  = (u16*)(ws + (137llu<<20));
  u16*   Woutb = (u16*)(ws + (145llu<<20));
  u16*   yg    = (u16*)(ws + (149llu<<20));
  float* hend  = (float*)(ws + (181llu<<20));
  float* sumdt = (float*)(ws + (189llu<<20));
  float* hin   = (float*)(ws + (190llu<<20));

  wcvt_kernel<<<(D_MODEL*2*D_INNER)/1024, 256, 0, stream>>>(W1,  W1b,  D_MODEL*2*D_INNER);
  wcvt_kernel<<<(D_INNER*D_INNER)/1024,  256, 0, stream>>>(Wdt, Wdtb, D_INNER*D_INNER);
  wcvt_kernel<<<(D_INNER*D_MODEL)/1024,  256, 0, stream>>>(Wout,Woutb,D_INNER*D_MODEL);

  ln_kernel<<<NROWS, 256, 0, stream>>>(x, lng, lnb, xn);

  gemm_mfma<0><<<dim3(2*D_INNER/64, NROWS/64), 256, 0, stream>>>(
      xn, W1b, nullptr, nullptr, (void*)xz, NROWS, 2*D_INNER, D_MODEL);

  conv_silu_kernel<<<(NROWS*D_INNER)/256, 256, 0, stream>>>(xz, cw, cb, uu);

  xproj_kernel<<<NROWS/4, 256, 0, stream>>>(uu, Wx, Bm);

  gemm_mfma<1><<<dim3(D_INNER/64, NROWS/64), 256, 0, stream>>>(
      uu, Wdtb, dtb, nullptr, (void*)dlt, NROWS, D_INNER, D_INNER);

  scan_partial<<<dim3(D_INNER/256, BATCH, NCHUNK), 256, 0, stream>>>(
      uu, dlt, Bm, Alog, hend, sumdt);
  scan_combine<<<dim3(D_INNER/256, BATCH), 256, 0, stream>>>(
      hend, sumdt, Alog, hin);
  scan_final<<<dim3(D_INNER/256, BATCH, NCHUNK), 256, 0, stream>>>(
      uu, dlt, Bm, xz, Alog, Dpar, hin, yg);

  gemm_mfma<2><<<dim3(D_MODEL/64, NROWS/64), 256, 0, stream>>>(
      yg, Woutb, nullptr, x, d_out, NROWS, D_MODEL, D_INNER);

  (void)in_sizes; (void)n_in; (void)out_size; (void)ws_size;
}

// Round 6
// 892.457 us; speedup vs baseline: 2.4577x; 1.4150x over previous
//
#include <hip/hip_runtime.h>

typedef unsigned short u16;
typedef unsigned int   u32;

#define D_MODEL 1024
#define D_INNER 2048
#define D_STATE 16
#define SEQLEN  2048
#define BATCH   4
#define NROWS   (BATCH*SEQLEN)   // 8192
#define CHUNK   128
#define NCHUNK  (SEQLEN/CHUNK)   // 16

__device__ __forceinline__ float b2f(u16 v){
  union { u32 i; float f; } u; u.i = ((u32)v) << 16; return u.f;
}
__device__ __forceinline__ u16 f2b(float f){
  union { float f; u32 i; } u; u.f = f;
  u32 x = u.i;
  return (u16)((x + 0x7fffu + ((x >> 16) & 1u)) >> 16);  // RNE
}
__device__ __forceinline__ float h2f(u16 v){
  _Float16 h; __builtin_memcpy(&h, &v, 2); return (float)h;
}
__device__ __forceinline__ u16 f2h(float f){
  _Float16 h = (_Float16)f; u16 v; __builtin_memcpy(&v, &h, 2); return v;
}

typedef __bf16 bf16x8 __attribute__((ext_vector_type(8)));
typedef float  f32x4  __attribute__((ext_vector_type(4)));

// async global->LDS, 16B per lane; data for lane i lands at lds + i*16B.
__device__ __forceinline__ void async16(u16* lds, const u16* g){
  __builtin_amdgcn_global_load_lds(
      (const __attribute__((address_space(1))) void*)g,
      (__attribute__((address_space(3))) void*)lds,
      16, 0, 0);
}

// ---------------------------------------------------------------------------
// fp32 [Kd][Nd] -> bf16 transposed [Nd][Kd]   (32x32 LDS tiles)
// ---------------------------------------------------------------------------
__global__ __launch_bounds__(256) void wcvt_t_kernel(
    const float* __restrict__ W, u16* __restrict__ Bt, int Kd, int Nd)
{
  __shared__ u16 tile[32][33];
  const int n0 = blockIdx.x*32, k0 = blockIdx.y*32;
  const int tx = threadIdx.x & 31, ty = threadIdx.x >> 5;  // ty 0..7
  #pragma unroll
  for (int i=0;i<32;i+=8)
    tile[ty+i][tx] = f2b(W[(size_t)(k0+ty+i)*Nd + n0+tx]);   // tile[k][n]
  __syncthreads();
  #pragma unroll
  for (int i=0;i<32;i+=8)
    Bt[(size_t)(n0+ty+i)*Kd + k0+tx] = tile[tx][ty+i];
}

// ---------------------------------------------------------------------------
// Fused LayerNorm: x[row][1024] fp32 -> xn bf16
// ---------------------------------------------------------------------------
__global__ __launch_bounds__(256) void ln_kernel(
    const float* __restrict__ x, const float* __restrict__ g,
    const float* __restrict__ be, u16* __restrict__ xn)
{
  const int row = blockIdx.x;
  const float* xr = x + (size_t)row * D_MODEL;
  const int tid = threadIdx.x;
  float v[4]; float s = 0.f, s2 = 0.f;
  #pragma unroll
  for (int j=0;j<4;j++){
    float f = xr[tid + 256*j];
    v[j] = f; s += f; s2 += f*f;
  }
  #pragma unroll
  for (int o=32;o>0;o>>=1){ s += __shfl_down(s,o); s2 += __shfl_down(s2,o); }
  __shared__ float sh[8];
  const int wave = tid>>6, lane = tid&63;
  if (lane==0){ sh[wave]=s; sh[4+wave]=s2; }
  __syncthreads();
  const float ts  = sh[0]+sh[1]+sh[2]+sh[3];
  const float ts2 = sh[4]+sh[5]+sh[6]+sh[7];
  const float mu  = ts * (1.f/D_MODEL);
  const float var = ts2 * (1.f/D_MODEL) - mu*mu;
  const float rstd = rsqrtf(var + 1e-5f);
  u16* xo = xn + (size_t)row * D_MODEL;
  #pragma unroll
  for (int j=0;j<4;j++){
    int i = tid + 256*j;
    xo[i] = f2b((v[j]-mu)*rstd * g[i] + be[i]);
  }
}

// ---------------------------------------------------------------------------
// 128x128x32 MFMA GEMM with global_load_lds staging.
// A [M][K] bf16 row-major ; Bt [N][K] bf16 row-major (pre-transposed weight).
// LDS tiles: 128 rows x 32 k, 64B rows, XOR-swizzled 16B granules:
//   phys_granule = logical_granule ^ ((row>>1)&3)
// -> staging is lane-contiguous (global_load_lds OK) and ds_read_b128 of
//    fragments hits all 8 bank-quads with 2 lanes each (2-way = free, m136).
// Wave grid 2x2: wave handles 64m x 64n = 4x4 16x16x32 MFMA accs.
// EPI 0: bf16 ; EPI 1: softplus(v+bias)->fp16 ; EPI 2: v+resid->fp32
// ---------------------------------------------------------------------------
template<int EPI>
__global__ __launch_bounds__(256) void gemm_mfma128(
    const u16* __restrict__ A, const u16* __restrict__ Bt,
    const float* __restrict__ bias, const float* __restrict__ resid,
    void* __restrict__ outv, int M, int N, int K)
{
  __shared__ __align__(16) u16 As[128*32];
  __shared__ __align__(16) u16 Bs[128*32];
  const int tid  = threadIdx.x;
  const int wave = tid >> 6, lane = tid & 63;
  const int quad = lane >> 4, l16 = lane & 15;
  const int m0 = blockIdx.y*128, n0 = blockIdx.x*128;
  const int wm = (wave & 1)*64, wn = (wave >> 1)*64;

  // staging: wave covers rows wave*32 .. wave*32+31 of both tiles (2 insts each)
  const int srow = wave*32 + (lane >> 2);            // +0 / +16 for q=0/1
  const int gcol = ((lane & 3) ^ ((lane >> 3) & 3)) * 8;  // swizzled granule
  const u16* pA = A  + (size_t)(m0 + srow)*K + gcol;
  const u16* pB = Bt + (size_t)(n0 + srow)*K + gcol;
  u16* lA = &As[(wave*32)*32];
  u16* lB = &Bs[(wave*32)*32];

  // fragment LDS byte offsets (2-way-conflict-free by swizzle)
  const int sw  = quad ^ ((l16 >> 1) & 3);
  const int aoff = (wm + l16)*64 + sw*16;   // + mf*1024
  const int boff = (wn + l16)*64 + sw*16;   // + nf*1024

  f32x4 acc[4][4];
  #pragma unroll
  for (int i=0;i<4;i++)
    #pragma unroll
    for (int j=0;j<4;j++) acc[i][j] = (f32x4){0.f,0.f,0.f,0.f};

  for (int k0 = 0; k0 < K; k0 += 32) {
    __syncthreads();                       // prev fragments consumed
    async16(lA,          pA + k0);
    async16(lA + 16*32,  pA + (size_t)16*K + k0);
    async16(lB,          pB + k0);
    async16(lB + 16*32,  pB + (size_t)16*K + k0);
    __syncthreads();                       // staging drained (vmcnt(0))

    bf16x8 afr[4], bfr[4];
    #pragma unroll
    for (int mf=0; mf<4; mf++)
      afr[mf] = *reinterpret_cast<const bf16x8*>((const char*)As + aoff + mf*1024);
    #pragma unroll
    for (int nf=0; nf<4; nf++)
      bfr[nf] = *reinterpret_cast<const bf16x8*>((const char*)Bs + boff + nf*1024);
    #pragma unroll
    for (int mf=0; mf<4; mf++)
      #pragma unroll
      for (int nf=0; nf<4; nf++)
        acc[mf][nf] = __builtin_amdgcn_mfma_f32_16x16x32_bf16(afr[mf], bfr[nf], acc[mf][nf], 0, 0, 0);
  }

  #pragma unroll
  for (int mf=0; mf<4; mf++){
    #pragma unroll
    for (int nf=0; nf<4; nf++){
      const int col = n0 + wn + nf*16 + l16;
      #pragma unroll
      for (int j=0;j<4;j++){
        const int row = m0 + wm + mf*16 + quad*4 + j;
        float v = acc[mf][nf][j];
        if (EPI == 1) {
          v += bias[col];
          v = (v > 20.f) ? v : log1pf(__expf(v));
          ((u16*)outv)[(size_t)row*N + col] = f2h(v);       // delta fp16
        } else if (EPI == 2) {
          v += resid[(size_t)row*N + col];
          ((float*)outv)[(size_t)row*N + col] = v;          // final out fp32
        } else {
          ((u16*)outv)[(size_t)row*N + col] = f2b(v);       // bf16 activation
        }
      }
    }
  }
}

// ---------------------------------------------------------------------------
// Causal depthwise conv(width 4) + bias + SiLU.  u_pre = xz[:, 0:2048] (bf16).
// ---------------------------------------------------------------------------
__global__ __launch_bounds__(256) void conv_silu_kernel(
    const u16* __restrict__ xz, const float* __restrict__ cw,
    const float* __restrict__ cb, u16* __restrict__ u)
{
  const int idx = blockIdx.x*256 + threadIdx.x;  // = bt*2048 + c
  const int c  = idx & (D_INNER-1);
  const int t  = (idx >> 11) & (SEQLEN-1);
  const int bt = idx >> 11;
  float acc = cb[c];
  #pragma unroll
  for (int k=0;k<4;k++){
    int tt = t - 3 + k;
    if (tt >= 0)
      acc += cw[c*4 + k] * b2f(xz[(size_t)(bt - 3 + k)*4096 + c]);
  }
  float sv = acc / (1.f + __expf(-acc));
  u[(size_t)bt*D_INNER + c] = f2b(sv);
}

// ---------------------------------------------------------------------------
// x_proj: only cols 16..31 (the B matrix) are consumed downstream.
// ---------------------------------------------------------------------------
__global__ __launch_bounds__(256) void xproj_kernel(
    const u16* __restrict__ u, const float* __restrict__ W, float* __restrict__ Bm)
{
  const int wave = threadIdx.x >> 6, lane = threadIdx.x & 63;
  const int m = blockIdx.x*4 + wave;
  const int n = lane & 15, kq = lane >> 4;
  const u16* ur = u + (size_t)m*D_INNER + (size_t)kq*512;
  float acc = 0.f;
  for (int i=0;i<512;i++)
    acc += b2f(ur[i]) * W[(size_t)(kq*512 + i)*32 + 16 + n];
  acc += __shfl_xor(acc, 16);
  acc += __shfl_xor(acc, 32);
  if (lane < 16) Bm[(size_t)m*16 + n] = acc;
}

// ---------------------------------------------------------------------------
// Chunked selective scan, 3 passes (exact linear-recurrence decomposition).
// ---------------------------------------------------------------------------
__global__ __launch_bounds__(256) void scan_partial(
    const u16* __restrict__ uu, const u16* __restrict__ delta16,
    const float* __restrict__ Bm, const float* __restrict__ Alog,
    float* __restrict__ hend, float* __restrict__ sumdt)
{
  const int b = blockIdx.y, ch = blockIdx.z;
  const int c = blockIdx.x*256 + threadIdx.x;
  const int row0 = b*SEQLEN + ch*CHUNK;
  float A[16], h[16];
  #pragma unroll
  for (int s=0;s<16;s++){ A[s] = -__expf(Alog[c*16+s]); h[s]=0.f; }
  __shared__ float Bsh[CHUNK*16];
  const float* src = Bm + (size_t)row0*16;
  #pragma unroll
  for (int j=0;j<8;j++) Bsh[threadIdx.x + 256*j] = src[threadIdx.x + 256*j];
  __syncthreads();

  float S = 0.f;
  float dta[8], uva[8], dtb[8], uvb[8];
  #pragma unroll
  for (int j=0;j<8;j++){
    size_t r = (size_t)(row0+j);
    dta[j] = h2f(delta16[r*D_INNER+c]);
    uva[j] = b2f(uu[r*D_INNER+c]);
  }
  #pragma unroll 1
  for (int g=0; g<CHUNK; g+=16){
    #pragma unroll
    for (int j=0;j<8;j++){
      int tl = g+8+j; tl = tl < CHUNK ? tl : CHUNK-1;
      size_t r = (size_t)(row0+tl);
      dtb[j] = h2f(delta16[r*D_INNER+c]);
      uvb[j] = b2f(uu[r*D_INNER+c]);
    }
    #pragma unroll
    for (int j=0;j<8;j++){
      float dt=dta[j], uv=uva[j]; S += dt; float xv=dt*uv;
      const float* Bt = &Bsh[(g+j)*16];
      #pragma unroll
      for (int s=0;s<16;s++) h[s] = fmaf(h[s], __expf(dt*A[s]), xv*Bt[s]);
    }
    #pragma unroll
    for (int j=0;j<8;j++){
      int tl = g+16+j; tl = tl < CHUNK ? tl : CHUNK-1;
      size_t r = (size_t)(row0+tl);
      dta[j] = h2f(delta16[r*D_INNER+c]);
      uva[j] = b2f(uu[r*D_INNER+c]);
    }
    #pragma unroll
    for (int j=0;j<8;j++){
      float dt=dtb[j], uv=uvb[j]; S += dt; float xv=dt*uv;
      const float* Bt = &Bsh[(g+8+j)*16];
      #pragma unroll
      for (int s=0;s<16;s++) h[s] = fmaf(h[s], __expf(dt*A[s]), xv*Bt[s]);
    }
  }
  const size_t base = ((size_t)(b*NCHUNK+ch)*16)*D_INNER + c;
  #pragma unroll
  for (int s=0;s<16;s++) hend[base + (size_t)s*D_INNER] = h[s];
  sumdt[(size_t)(b*NCHUNK+ch)*D_INNER + c] = S;
}

__global__ __launch_bounds__(256) void scan_combine(
    const float* __restrict__ hend, const float* __restrict__ sumdt,
    const float* __restrict__ Alog, float* __restrict__ hin)
{
  const int b = blockIdx.y;
  const int c = blockIdx.x*256 + threadIdx.x;
  float A[16], h[16];
  #pragma unroll
  for (int s=0;s<16;s++){ A[s] = -__expf(Alog[c*16+s]); h[s]=0.f; }
  #pragma unroll 1
  for (int k=0;k<NCHUNK;k++){
    const size_t base = ((size_t)(b*NCHUNK+k)*16)*D_INNER + c;
    #pragma unroll
    for (int s=0;s<16;s++) hin[base + (size_t)s*D_INNER] = h[s];
    const float S = sumdt[(size_t)(b*NCHUNK+k)*D_INNER + c];
    #pragma unroll
    for (int s=0;s<16;s++)
      h[s] = fmaf(h[s], __expf(S*A[s]), hend[base + (size_t)s*D_INNER]);
  }
}

__global__ __launch_bounds__(256) void scan_final(
    const u16* __restrict__ uu, const u16* __restrict__ delta16,
    const float* __restrict__ Bm, const u16* __restrict__ xz,
    const float* __restrict__ Alog, const float* __restrict__ Dpar,
    const float* __restrict__ hin, u16* __restrict__ yg)
{
  const int b = blockIdx.y, ch = blockIdx.z;
  const int c = blockIdx.x*256 + threadIdx.x;
  const int row0 = b*SEQLEN + ch*CHUNK;
  float A[16], h[16];
  const size_t base = ((size_t)(b*NCHUNK+ch)*16)*D_INNER + c;
  #pragma unroll
  for (int s=0;s<16;s++){
    A[s] = -__expf(Alog[c*16+s]);
    h[s] = hin[base + (size_t)s*D_INNER];
  }
  const float Dc = Dpar[c];
  __shared__ float Bsh[CHUNK*16];
  const float* src = Bm + (size_t)row0*16;
  #pragma unroll
  for (int j=0;j<8;j++) Bsh[threadIdx.x + 256*j] = src[threadIdx.x + 256*j];
  __syncthreads();

  float dta[8], uva[8], zva[8], dtb[8], uvb[8], zvb[8];
  #pragma unroll
  for (int j=0;j<8;j++){
    size_t r = (size_t)(row0+j);
    dta[j] = h2f(delta16[r*D_INNER+c]);
    uva[j] = b2f(uu[r*D_INNER+c]);
    zva[j] = b2f(xz[r*4096 + D_INNER + c]);
  }
  #pragma unroll 1
  for (int g=0; g<CHUNK; g+=16){
    #pragma unroll
    for (int j=0;j<8;j++){
      int tl = g+8+j; tl = tl < CHUNK ? tl : CHUNK-1;
      size_t r = (size_t)(row0+tl);
      dtb[j] = h2f(delta16[r*D_INNER+c]);
      uvb[j] = b2f(uu[r*D_INNER+c]);
      zvb[j] = b2f(xz[r*4096 + D_INNER + c]);
    }
    #pragma unroll
    for (int j=0;j<8;j++){
      float dt=dta[j], uv=uva[j], zv=zva[j];
      float xv=dt*uv, y=0.f;
      const float* Bt = &Bsh[(g+j)*16];
      #pragma unroll
      for (int s=0;s<16;s++){
        h[s] = fmaf(h[s], __expf(dt*A[s]), xv*Bt[s]);
        y += h[s];
      }
      y = fmaf(uv, Dc, y);
      float gz = zv/(1.f+__expf(-zv));
      yg[(size_t)(row0+g+j)*D_INNER + c] = f2b(y*gz);
    }
    #pragma unroll
    for (int j=0;j<8;j++){
      int tl = g+16+j; tl = tl < CHUNK ? tl : CHUNK-1;
      size_t r = (size_t)(row0+tl);
      dta[j] = h2f(delta16[r*D_INNER+c]);
      uva[j] = b2f(uu[r*D_INNER+c]);
      zva[j] = b2f(xz[r*4096 + D_INNER + c]);
    }
    #pragma unroll
    for (int j=0;j<8;j++){
      float dt=dtb[j], uv=uvb[j], zv=zvb[j];
      float xv=dt*uv, y=0.f;
      const float* Bt = &Bsh[(g+8+j)*16];
      #pragma unroll
      for (int s=0;s<16;s++){
        h[s] = fmaf(h[s], __expf(dt*A[s]), xv*Bt[s]);
        y += h[s];
      }
      y = fmaf(uv, Dc, y);
      float gz = zv/(1.f+__expf(-zv));
      yg[(size_t)(row0+g+8+j)*D_INNER + c] = f2b(y*gz);
    }
  }
}

// ---------------------------------------------------------------------------
extern "C" void kernel_launch(void* const* d_in, const int* in_sizes, int n_in,
                              void* d_out, int out_size, void* d_ws, size_t ws_size,
                              hipStream_t stream)
{
  const float* x    = (const float*)d_in[0];
  const float* lng  = (const float*)d_in[1];
  const float* lnb  = (const float*)d_in[2];
  const float* W1   = (const float*)d_in[3];
  const float* cw   = (const float*)d_in[4];
  const float* cb   = (const float*)d_in[5];
  const float* Wx   = (const float*)d_in[6];
  const float* Wdt  = (const float*)d_in[7];
  const float* dtb  = (const float*)d_in[8];
  const float* Alog = (const float*)d_in[9];
  const float* Dpar = (const float*)d_in[10];
  const float* Wout = (const float*)d_in[11];

  // workspace layout (MiB offsets), total 198 MiB:
  //  [0,32)      delta fp16 8192x2048   ([0,16) doubles as xn bf16, dead pre-gemm1)
  //  [32,96)     xz bf16 8192x4096
  //  [96,128)    uu bf16 8192x2048
  //  [128,128.5) Bm fp32 8192x16
  //  [129,137)   W1t bf16 [4096][1024] ; [137,145) Wdtt bf16 [2048][2048] ;
  //  [145,149)   Woutt bf16 [1024][2048]
  //  [149,181)   yg bf16 8192x2048
  //  [181,189)   hend fp32 ; [189,189.5) sumdt fp32 ; [190,198) hin fp32
  char* ws = (char*)d_ws;
  u16*   dlt   = (u16*)(ws);
  u16*   xn    = (u16*)(ws);                 // alias (sequenced)
  u16*   xz    = (u16*)(ws + (32llu<<20));
  u16*   uu    = (u16*)(ws + (96llu<<20));
  float* Bm    = (float*)(ws + (128llu<<20));
  u16*   W1t   = (u16*)(ws + (129llu<<20));
  u16*   Wdtt  = (u16*)(ws + (137llu<<20));
  u16*   Woutt = (u16*)(ws + (145llu<<20));
  u16*   yg    = (u16*)(ws + (149llu<<20));
  float* hend  = (float*)(ws + (181llu<<20));
  float* sumdt = (float*)(ws + (189llu<<20));
  float* hin   = (float*)(ws + (190llu<<20));

  // weights -> bf16, transposed to [N][K]
  wcvt_t_kernel<<<dim3(2*D_INNER/32, D_MODEL/32), 256, 0, stream>>>(W1,  W1t,  D_MODEL, 2*D_INNER);
  wcvt_t_kernel<<<dim3(D_INNER/32,  D_INNER/32), 256, 0, stream>>>(Wdt, Wdtt, D_INNER, D_INNER);
  wcvt_t_kernel<<<dim3(D_MODEL/32,  D_INNER/32), 256, 0, stream>>>(Wout,Woutt,D_INNER, D_MODEL);

  ln_kernel<<<NROWS, 256, 0, stream>>>(x, lng, lnb, xn);

  gemm_mfma128<0><<<dim3(2*D_INNER/128, NROWS/128), 256, 0, stream>>>(
      xn, W1t, nullptr, nullptr, (void*)xz, NROWS, 2*D_INNER, D_MODEL);

  conv_silu_kernel<<<(NROWS*D_INNER)/256, 256, 0, stream>>>(xz, cw, cb, uu);

  xproj_kernel<<<NROWS/4, 256, 0, stream>>>(uu, Wx, Bm);

  gemm_mfma128<1><<<dim3(D_INNER/128, NROWS/128), 256, 0, stream>>>(
      uu, Wdtt, dtb, nullptr, (void*)dlt, NROWS, D_INNER, D_INNER);

  scan_partial<<<dim3(D_INNER/256, BATCH, NCHUNK), 256, 0, stream>>>(
      uu, dlt, Bm, Alog, hend, sumdt);
  scan_combine<<<dim3(D_INNER/256, BATCH), 256, 0, stream>>>(
      hend, sumdt, Alog, hin);
  scan_final<<<dim3(D_INNER/256, BATCH, NCHUNK), 256, 0, stream>>>(
      uu, dlt, Bm, xz, Alog, Dpar, hin, yg);

  gemm_mfma128<2><<<dim3(D_MODEL/128, NROWS/128), 256, 0, stream>>>(
      yg, Woutt, nullptr, x, d_out, NROWS, D_MODEL, D_INNER);

  (void)in_sizes; (void)n_in; (void)out_size; (void)ws_size;
}